// Round 5
// baseline (130.834 us; speedup 1.0000x reference)
//
#include <hip/hip_runtime.h>
#include <hip/hip_fp16.h>

// Triangulated-bilinear interp, B=8, N=262144 (512x512), T=2M targets.
// Round-10: quad-interleaved rec layout. Evidence: three structural MLP
// variations (R3 batch, TPT=8, R4 persistent pipeline) all land at 44-47us
// with FETCH fixed at 37MB -> in-flight gather lines/CU capped ~32 by HW
// (MSHR-class). Time model: lines/CU x L2-latency / MSHR. Only remaining
// lever: fewer distinct 64B lines per target. Layout slot(i,j) =
// (j>>1)*2nx + 2i + (j&1): each 64B line = 2x2 point quad at even anchors.
// Triangle (3 pts) E[lines] = 2.0 vs 2.25 row-major (-11%). Loads stay
// 3x dwordx4; only index math changes. Builder emits quad layout with one
// contiguous 64B store per quad. Pipeline/nt-stores/grid unchanged (R4).

typedef float  f32x4 __attribute__((ext_vector_type(4)));
typedef unsigned int u32x4 __attribute__((ext_vector_type(4)));

__device__ __forceinline__ unsigned pack_h2(float lo, float hi) {
    union { __half2 h2; unsigned u; } cv;
    cv.h2 = __float22half2_rn(make_float2(lo, hi));
    return cv.u;
}

__device__ __forceinline__ u32x4 pack8(const float* v) {
    u32x4 r;
    r[0] = pack_h2(v[0], v[1]);
    r[1] = pack_h2(v[2], v[3]);
    r[2] = pack_h2(v[4], v[5]);
    r[3] = pack_h2(v[6], v[7]);
    return r;
}

// Quad builder: thread owns quad (2qi..2qi+1, 2qj..2qj+1).
// slot(i,j) = (j>>1)*2*nx + 2*i + (j&1) -> quad = 4 consecutive slots
// = one contiguous 64B store. Loads: float2 per batch per row (coalesced;
// scalar path for odd nx to keep 8B alignment).
__global__ __launch_bounds__(256) void build_grid_quad(
    const float* __restrict__ x,   // (B=8, N)
    u32x4* __restrict__ rec,       // (ceil(ny/2)*2*nx) 16B per grid point
    const int* __restrict__ nx_p,
    int N)
{
    const int nx = *nx_p;
    const int ny = N / nx;
    const int qx = (nx + 1) >> 1;
    const int qy = (ny + 1) >> 1;
    const int nq = qx * qy;
    const int q = blockIdx.x * blockDim.x + threadIdx.x;
    if (q >= nq) return;
    const int qi = q % qx;
    const int qj = q / qx;
    const int i = qi << 1;
    const int j = qj << 1;
    const bool i1 = (i + 1 < nx);
    const bool j1 = (j + 1 < ny);
    const bool vec2 = ((nx & 1) == 0);   // float2 loads stay 8B-aligned
    const long base = (long)j * nx + i;

    float a0[8], a1[8], b0[8], b1[8];    // (i,j) (i+1,j) (i,j+1) (i+1,j+1)
    #pragma unroll
    for (int b = 0; b < 8; ++b) {
        const float* xb = x + (long)b * N;
        if (i1 && vec2) {
            float2 t = *reinterpret_cast<const float2*>(xb + base);
            a0[b] = t.x; a1[b] = t.y;
        } else {
            a0[b] = xb[base];
            a1[b] = i1 ? xb[base + 1] : 0.0f;
        }
        if (j1) {
            if (i1 && vec2) {
                float2 t = *reinterpret_cast<const float2*>(xb + base + nx);
                b0[b] = t.x; b1[b] = t.y;
            } else {
                b0[b] = xb[base + nx];
                b1[b] = i1 ? xb[base + nx + 1] : 0.0f;
            }
        } else { b0[b] = 0.0f; b1[b] = 0.0f; }
    }

    const long s = ((long)qj * nx + i) * 2;   // (j>>1)*2nx + 2i
    rec[s] = pack8(a0);
    if (j1) rec[s + 1] = pack8(b0);
    if (i1) {
        rec[s + 2] = pack8(a1);
        if (j1) rec[s + 3] = pack8(b1);
    }
}

__device__ __forceinline__ void half8_to_float8(u32x4 u, float* f) {
    union { u32x4 v; __half2 h2[4]; } cv;
    cv.v = u;
    float2 a = __half22float2(cv.h2[0]); f[0] = a.x; f[1] = a.y;
    float2 b = __half22float2(cv.h2[1]); f[2] = b.x; f[3] = b.y;
    float2 c = __half22float2(cv.h2[2]); f[4] = c.x; f[5] = c.y;
    float2 d = __half22float2(cv.h2[3]); f[6] = d.x; f[7] = d.y;
}

#define TPT 4   // targets per chunk

#define LOAD_TGT(c, tx, ty) do {                                          \
    const int _t0 = (c) * TPT;                                            \
    tx = __builtin_nontemporal_load(                                      \
        reinterpret_cast<const f32x4*>(tgt_x + _t0));                     \
    ty = __builtin_nontemporal_load(                                      \
        reinterpret_cast<const f32x4*>(tgt_y + _t0));                     \
} while (0)

// Quad-layout gather: sA=(i,j), sB=(i+1,j), sC=(i,j+1), sD=(i+1,j+1).
// sA = (j>>1)*2nx + 2i + (j&1); sB = sA+2; sC = sA + (j odd ? 2nx-1 : 1);
// sD = sC+2. Triangle: lower -> {sA,sB,sC}, upper -> {sD,sB,sC}.
#define GATHER(tx, ty, w0, w1, w2, r0, r1, r2) do {                       \
    _Pragma("unroll")                                                     \
    for (int k = 0; k < TPT; ++k) {                                       \
        float fx = (tx[k] - x0) * rdx;                                    \
        float fy = (ty[k] - y0) * rdy;                                    \
        float ix = fminf(fmaxf(floorf(fx), 0.0f), ixmax);                 \
        float iy = fminf(fmaxf(floorf(fy), 0.0f), iymax);                 \
        float u = fx - ix;                                                \
        float v = fy - iy;                                                \
        bool lower = (u + v) <= 1.0f;                                     \
        int i0 = (int)ix, j0 = (int)iy;                                   \
        int sA = (j0 >> 1) * nx2 + (i0 << 1) + (j0 & 1);                  \
        int sC = sA + ((j0 & 1) ? (nx2 - 1) : 1);                         \
        w0[k] = lower ? (1.0f - u - v) : (u + v - 1.0f);                  \
        w1[k] = lower ? u : (1.0f - v);                                   \
        w2[k] = lower ? v : (1.0f - u);                                   \
        r0[k] = rec[lower ? sA : (sC + 2)];                               \
        r1[k] = rec[sA + 2];                                              \
        r2[k] = rec[sC];                                                  \
    }                                                                     \
} while (0)

#define CONSUME(c, w0, w1, w2, r0, r1, r2) do {                           \
    const int _t0 = (c) * TPT;                                            \
    float res[TPT][8];                                                    \
    _Pragma("unroll")                                                     \
    for (int k = 0; k < TPT; ++k) {                                       \
        float f0[8], f1[8], f2[8];                                        \
        half8_to_float8(r0[k], f0);                                       \
        half8_to_float8(r1[k], f1);                                       \
        half8_to_float8(r2[k], f2);                                       \
        _Pragma("unroll")                                                 \
        for (int b = 0; b < 8; ++b)                                       \
            res[k][b] = f0[b] * w0[k] + f1[b] * w1[k] + f2[b] * w2[k];    \
    }                                                                     \
    _Pragma("unroll")                                                     \
    for (int b = 0; b < 8; ++b) {                                         \
        f32x4 r4 = { res[0][b], res[1][b], res[2][b], res[3][b] };        \
        __builtin_nontemporal_store(                                      \
            r4, reinterpret_cast<f32x4*>(out + (long)b * T + _t0));       \
    }                                                                     \
} while (0)

__global__ __launch_bounds__(256, 2) void interp_pipe_kernel(
    const u32x4* __restrict__ rec,   // quad layout, L2-resident
    const float* __restrict__ src_x,
    const float* __restrict__ src_y,
    const float* __restrict__ tgt_x,
    const float* __restrict__ tgt_y,
    const int* __restrict__ nx_p,
    float* __restrict__ out,
    int T, int N)
{
    const int nx = *nx_p;
    const int ny = N / nx;
    const int nx2 = nx * 2;
    const float x0 = src_x[0];
    const float x1 = src_x[nx - 1];
    const float y0 = src_y[0];
    const float y1 = src_y[N - 1];
    const float rdx = (float)(nx - 1) / (x1 - x0);
    const float rdy = (float)(ny - 1) / (y1 - y0);
    const float ixmax = (float)(nx - 2);
    const float iymax = (float)(ny - 2);

    const int nch = T / TPT;                       // full chunks
    const int gsz = gridDim.x * blockDim.x;
    const int tid = blockIdx.x * blockDim.x + threadIdx.x;

    // Scalar tail for T % TPT leftovers (none at T=2M, kept for generality).
    {
        const int tail0 = nch * TPT;
        if (tid < T - tail0) {
            const int t = tail0 + tid;
            float fx = (tgt_x[t] - x0) * rdx;
            float fy = (tgt_y[t] - y0) * rdy;
            float ix = fminf(fmaxf(floorf(fx), 0.0f), ixmax);
            float iy = fminf(fmaxf(floorf(fy), 0.0f), iymax);
            float u = fx - ix;
            float v = fy - iy;
            bool lower = (u + v) <= 1.0f;
            int i0 = (int)ix, j0 = (int)iy;
            int sA = (j0 >> 1) * nx2 + (i0 << 1) + (j0 & 1);
            int sC = sA + ((j0 & 1) ? (nx2 - 1) : 1);
            u32x4 q0 = rec[lower ? sA : (sC + 2)];
            u32x4 q1 = rec[sA + 2];
            u32x4 q2 = rec[sC];
            float w0 = lower ? (1.0f - u - v) : (u + v - 1.0f);
            float w1 = lower ? u : (1.0f - v);
            float w2 = lower ? v : (1.0f - u);
            float f0[8], f1[8], f2[8];
            half8_to_float8(q0, f0);
            half8_to_float8(q1, f1);
            half8_to_float8(q2, f2);
            for (int b = 0; b < 8; ++b)
                out[(long)b * T + t] = f0[b] * w0 + f1[b] * w1 + f2[b] * w2;
        }
    }

    int cCur = tid;
    if (cCur >= nch) return;
    int cNxt = cCur + gsz;
    int cPre = cNxt + gsz;

    // Two disjoint register stages (A/B); rotation by code duplication so
    // every array index is compile-time (rule: no runtime-indexed regs).
    f32x4 txA, tyA, txB, tyB;
    float wA0[TPT], wA1[TPT], wA2[TPT];
    float wB0[TPT], wB1[TPT], wB2[TPT];
    u32x4 rA0[TPT], rA1[TPT], rA2[TPT];
    u32x4 rB0[TPT], rB1[TPT], rB2[TPT];

    LOAD_TGT(cCur, txA, tyA);
    bool haveNxt = (cNxt < nch);
    if (haveNxt) LOAD_TGT(cNxt, txB, tyB);
    GATHER(txA, tyA, wA0, wA1, wA2, rA0, rA1, rA2);

    while (true) {
        // ---- CUR = A ----
        if (!haveNxt) { CONSUME(cCur, wA0, wA1, wA2, rA0, rA1, rA2); break; }
        if (cPre < nch) LOAD_TGT(cPre, txA, tyA);   // txA free (already consumed)
        GATHER(txB, tyB, wB0, wB1, wB2, rB0, rB1, rB2);
        CONSUME(cCur, wA0, wA1, wA2, rA0, rA1, rA2);
        cCur = cNxt; cNxt = cPre; cPre += gsz;
        haveNxt = (cNxt < nch);
        // ---- CUR = B ----
        if (!haveNxt) { CONSUME(cCur, wB0, wB1, wB2, rB0, rB1, rB2); break; }
        if (cPre < nch) LOAD_TGT(cPre, txB, tyB);
        GATHER(txA, tyA, wA0, wA1, wA2, rA0, rA1, rA2);
        CONSUME(cCur, wB0, wB1, wB2, rB0, rB1, rB2);
        cCur = cNxt; cNxt = cPre; cPre += gsz;
        haveNxt = (cNxt < nch);
    }
}

// Fallback: direct fp32 path, used only if ws too small / B != 8.
__global__ __launch_bounds__(256) void interp_fallback_kernel(
    const float* __restrict__ x,
    const float* __restrict__ src_x,
    const float* __restrict__ src_y,
    const float* __restrict__ tgt_x,
    const float* __restrict__ tgt_y,
    const int* __restrict__ nx_p,
    float* __restrict__ out,
    int T, int N, int B)
{
    const int nx = *nx_p;
    const int ny = N / nx;
    const float x0 = src_x[0];
    const float x1 = src_x[nx - 1];
    const float y0 = src_y[0];
    const float y1 = src_y[N - 1];
    const float rdx = (float)(nx - 1) / (x1 - x0);
    const float rdy = (float)(ny - 1) / (y1 - y0);

    const int t = blockIdx.x * blockDim.x + threadIdx.x;
    if (t >= T) return;
    float fx = (tgt_x[t] - x0) * rdx;
    float fy = (tgt_y[t] - y0) * rdy;
    float ix = fminf(fmaxf(floorf(fx), 0.0f), (float)(nx - 2));
    float iy = fminf(fmaxf(floorf(fy), 0.0f), (float)(ny - 2));
    float u = fx - ix;
    float v = fy - iy;
    int base = (int)iy * nx + (int)ix;
    bool lower = (u + v) <= 1.0f;
    int   i0 = lower ? base : (base + nx + 1);
    int   i1 = base + 1;
    int   i2 = base + nx;
    float w0 = lower ? (1.0f - u - v) : (u + v - 1.0f);
    float w1 = lower ? u : (1.0f - v);
    float w2 = lower ? v : (1.0f - u);
    for (int b = 0; b < B; ++b) {
        const float* xb = x + (long)b * N;
        out[(long)b * T + t] = xb[i0] * w0 + xb[i1] * w1 + xb[i2] * w2;
    }
}

extern "C" void kernel_launch(void* const* d_in, const int* in_sizes, int n_in,
                              void* d_out, int out_size, void* d_ws, size_t ws_size,
                              hipStream_t stream) {
    const float* x     = (const float*)d_in[0];
    const float* src_x = (const float*)d_in[1];
    const float* src_y = (const float*)d_in[2];
    const float* tgt_x = (const float*)d_in[3];
    const float* tgt_y = (const float*)d_in[4];
    const int*   nx_p  = (const int*)d_in[5];
    float* out = (float*)d_out;

    const int N = in_sizes[1];            // nx*ny = 262144
    const int T = in_sizes[3];            // 2,000,000
    const int B = in_sizes[0] / N;        // 8

    // Quad layout needs ceil(ny/2)*2*nx slots <= N + nx <= 2N (host doesn't
    // know nx; use the conservative bound).
    const size_t rec_bytes = (size_t)N * 2 * 16;

    if (B == 8 && ws_size >= rec_bytes) {
        u32x4* rec = (u32x4*)d_ws;
        {
            // nq = ceil(nx/2)*ceil(ny/2) <= N/2 for any nx,ny >= 1.
            const int block = 256;
            const int grid = (N / 2 + block - 1) / block;
            build_grid_quad<<<grid, block, 0, stream>>>(x, rec, nx_p, N);
        }
        {
            const int nch = T / TPT;
            int grid = (nch + 255) / 256;
            if (grid > 512) grid = 512;      // 2 blocks/CU, fully resident
            if (grid < 1) grid = 1;
            interp_pipe_kernel<<<grid, 256, 0, stream>>>(
                rec, src_x, src_y, tgt_x, tgt_y, nx_p, out, T, N);
        }
    } else {
        const int block = 256;
        const int grid = (T + block - 1) / block;
        interp_fallback_kernel<<<grid, block, 0, stream>>>(
            x, src_x, src_y, tgt_x, tgt_y, nx_p, out, T, N, B);
    }
}